// Round 10
// baseline (112.318 us; speedup 1.0000x reference)
//
#include <hip/hip_runtime.h>

// BinaryLinear int8 path (round 10):
//   prep    : fused {X f32 -> i8 per-row quant + Sc} and {W -> {0,1} i8, NxK}
//   gemm_tex: 256x256 tile, 8 waves, NO LDS / NO barriers. MFMA fragments
//             loaded directly from global (16 rows x 64B coalesced segments,
//             L1-broadcast across waves, L2-resident operands via XCD swizzle).
//             3 register groups {A-lo, B, A-hi} reloaded for t+1 right after
//             their last use in tile t; compiler emits counted vmcnt.
//             mfma_i32_16x16x64_i8, f32 dequant epilogue.
// Fallback: round-1 fused bf16 kernel if ws too small.

#define MDIM 8192
#define NDIM 2048
#define KDIM 2048
#define NT   (KDIM / 128)         // 16 K-tiles of 128 i8

typedef __attribute__((ext_vector_type(8))) short short8;
typedef __attribute__((ext_vector_type(4))) float float4v;
typedef __attribute__((ext_vector_type(4))) float f32x4;
typedef __attribute__((ext_vector_type(4))) int int4v;
typedef __attribute__((ext_vector_type(4))) unsigned short ushort4v;
typedef __attribute__((ext_vector_type(8))) unsigned short ushort8v;

__device__ __forceinline__ unsigned short f2bf(float f) {
    union { float f; unsigned u; } v; v.f = f;
    unsigned r = v.u + 0x7FFFu + ((v.u >> 16) & 1u);
    return (unsigned short)(r >> 16);
}

#define FENCE asm volatile("" ::: "memory")

// ---------------- pass 1 (fused): quantize X rows + binarize/transpose W ----
__global__ __launch_bounds__(256) void prep(const float* __restrict__ X,
                                            const float* __restrict__ W,
                                            signed char* __restrict__ Xq,
                                            signed char* __restrict__ Wt,
                                            float* __restrict__ Sc) {
    __shared__ __align__(16) signed char T[64][80];
    __shared__ float wm[4];
    const int t = threadIdx.x;
    const int bid = blockIdx.x;

    if (bid < MDIM) {
        const int row = bid;
        const float* xr = X + (size_t)row * KDIM + t * 8;
        float4v a = *reinterpret_cast<const float4v*>(xr);
        float4v b = *reinterpret_cast<const float4v*>(xr + 4);
        float m = fabsf(a[0]);
        m = fmaxf(m, fabsf(a[1])); m = fmaxf(m, fabsf(a[2])); m = fmaxf(m, fabsf(a[3]));
        m = fmaxf(m, fabsf(b[0])); m = fmaxf(m, fabsf(b[1]));
        m = fmaxf(m, fabsf(b[2])); m = fmaxf(m, fabsf(b[3]));
#pragma unroll
        for (int off = 32; off; off >>= 1)
            m = fmaxf(m, __shfl_xor(m, off));
        if ((t & 63) == 0) wm[t >> 6] = m;
        __syncthreads();
        const float s = fmaxf(fmaxf(wm[0], wm[1]), fmaxf(wm[2], wm[3]));
        const float inv = (s > 0.f) ? 127.0f / s : 0.f;

        int q[8];
        q[0] = __float2int_rn(a[0] * inv); q[1] = __float2int_rn(a[1] * inv);
        q[2] = __float2int_rn(a[2] * inv); q[3] = __float2int_rn(a[3] * inv);
        q[4] = __float2int_rn(b[0] * inv); q[5] = __float2int_rn(b[1] * inv);
        q[6] = __float2int_rn(b[2] * inv); q[7] = __float2int_rn(b[3] * inv);
        unsigned lo = (q[0] & 255) | ((q[1] & 255) << 8) | ((q[2] & 255) << 16) | ((unsigned)(q[3] & 255) << 24);
        unsigned hi = (q[4] & 255) | ((q[5] & 255) << 8) | ((q[6] & 255) << 16) | ((unsigned)(q[7] & 255) << 24);
        unsigned* dst = (unsigned*)(Xq + (size_t)row * KDIM + t * 8);
        dst[0] = lo; dst[1] = hi;
        if (t == 0) Sc[row] = s * (1.0f / 127.0f);
    } else {
        const int wb = bid - MDIM;
        const int k0 = (wb >> 5) * 64;
        const int n0 = (wb & 31) * 64;
        const int kr = t >> 4;
        const int nc = (t & 15) * 4;
#pragma unroll
        for (int rr = 0; rr < 4; ++rr) {
            int k = k0 + rr * 16 + kr;
            float4v w4 = *reinterpret_cast<const float4v*>(W + (size_t)k * NDIM + n0 + nc);
#pragma unroll
            for (int c = 0; c < 4; ++c)
                T[nc + c][rr * 16 + kr] = (w4[c] > 0.0f) ? (signed char)1 : (signed char)0;
        }
        __syncthreads();
        const int row = t >> 2, ch = t & 3;
        int4v v = *reinterpret_cast<const int4v*>(&T[row][ch * 16]);
        *reinterpret_cast<int4v*>(Wt + (size_t)(n0 + row) * KDIM + k0 + ch * 16) = v;
    }
}

// ---------------- pass 2: 256x256 i8 GEMM, no LDS / no barriers ----------------
// Wave tile 128x64 = 8mi x 4ni 16x16 frags, 2 ks (K=64 each) per 128-B K-tile.
// Fragment load (direct from global): lane l (fr=l&15, fg=l>>4) reads 16 B at
//   row (base + mi*16 + fr), bytes [t*128 + ks*64 + fg*16).
// 16 rows x 64B aligned segments per wave-load; L1 broadcasts across waves.
// Reload groups for t+1 placed right after their last consumer in tile t.
__global__ __launch_bounds__(512, 2) void gemm_tex(const signed char* __restrict__ A,
                                                   const signed char* __restrict__ Bt,
                                                   const float* __restrict__ Sc,
                                                   float* __restrict__ O) {
    const int tid  = threadIdx.x;
    const int lane = tid & 63;
    const int w    = tid >> 6;       // 0..7
    const int wr   = w >> 2;         // 0..1
    const int wc   = w & 3;          // 0..3

    int id  = blockIdx.x;            // 256 blocks, %8==0 -> bijective
    int swz = (id & 7) * 32 + (id >> 3);
    const int bm = swz >> 3;         // 0..31
    const int bn = swz & 7;          // 0..7

    const int fr = lane & 15, fg = lane >> 4;
    const char* aB = (const char*)A + (size_t)(bm * 256 + wr * 128 + fr) * KDIM + fg * 16;
    const char* bB = (const char*)Bt + (size_t)(bn * 256 + wc * 64 + fr) * KDIM + fg * 16;

    int4v acc[8][4];
#pragma unroll
    for (int i = 0; i < 8; ++i)
#pragma unroll
        for (int j = 0; j < 4; ++j) {
            acc[i][j][0] = 0; acc[i][j][1] = 0; acc[i][j][2] = 0; acc[i][j][3] = 0;
        }

    int4v a1[4][2], a2[4][2], bf[4][2];

    // ---- prologue: load tile 0 (group order A-lo, B, A-hi) ----
#pragma unroll
    for (int mi = 0; mi < 4; ++mi)
#pragma unroll
        for (int ks = 0; ks < 2; ++ks)
            a1[mi][ks] = *reinterpret_cast<const int4v*>(aB + (size_t)mi * 16 * KDIM + ks * 64);
    FENCE;
#pragma unroll
    for (int ni = 0; ni < 4; ++ni)
#pragma unroll
        for (int ks = 0; ks < 2; ++ks)
            bf[ni][ks] = *reinterpret_cast<const int4v*>(bB + (size_t)ni * 16 * KDIM + ks * 64);
    FENCE;
#pragma unroll
    for (int mi = 0; mi < 4; ++mi)
#pragma unroll
        for (int ks = 0; ks < 2; ++ks)
            a2[mi][ks] = *reinterpret_cast<const int4v*>(aB + (size_t)(4 + mi) * 16 * KDIM + ks * 64);
    FENCE;

    for (int t = 0; t < NT; ++t) {
        const bool more = (t + 1 < NT);
        const char* aN = aB + (size_t)(t + 1) * 128;
        const char* bN = bB + (size_t)(t + 1) * 128;

        // ---- cluster 1: mi 0-3 (a1 x bf) ----
        __builtin_amdgcn_s_setprio(1);
#pragma unroll
        for (int mi = 0; mi < 4; ++mi)
#pragma unroll
            for (int ni = 0; ni < 4; ++ni) {
                acc[mi][ni] = __builtin_amdgcn_mfma_i32_16x16x64_i8(a1[mi][0], bf[ni][0], acc[mi][ni], 0, 0, 0);
                acc[mi][ni] = __builtin_amdgcn_mfma_i32_16x16x64_i8(a1[mi][1], bf[ni][1], acc[mi][ni], 0, 0, 0);
            }
        __builtin_amdgcn_s_setprio(0);
        FENCE;

        // ---- reload A-lo for t+1 (a1 dead; overlaps cluster 2) ----
        if (more) {
#pragma unroll
            for (int mi = 0; mi < 4; ++mi)
#pragma unroll
                for (int ks = 0; ks < 2; ++ks)
                    a1[mi][ks] = *reinterpret_cast<const int4v*>(aN + (size_t)mi * 16 * KDIM + ks * 64);
        }
        FENCE;

        // ---- cluster 2: mi 4-7 (a2 x bf) ----
        __builtin_amdgcn_s_setprio(1);
#pragma unroll
        for (int mi = 0; mi < 4; ++mi)
#pragma unroll
            for (int ni = 0; ni < 4; ++ni) {
                acc[4 + mi][ni] = __builtin_amdgcn_mfma_i32_16x16x64_i8(a2[mi][0], bf[ni][0], acc[4 + mi][ni], 0, 0, 0);
                acc[4 + mi][ni] = __builtin_amdgcn_mfma_i32_16x16x64_i8(a2[mi][1], bf[ni][1], acc[4 + mi][ni], 0, 0, 0);
            }
        __builtin_amdgcn_s_setprio(0);
        FENCE;

        // ---- reload B and A-hi for t+1 (both dead now) ----
        if (more) {
#pragma unroll
            for (int ni = 0; ni < 4; ++ni)
#pragma unroll
                for (int ks = 0; ks < 2; ++ks)
                    bf[ni][ks] = *reinterpret_cast<const int4v*>(bN + (size_t)ni * 16 * KDIM + ks * 64);
            FENCE;
#pragma unroll
            for (int mi = 0; mi < 4; ++mi)
#pragma unroll
                for (int ks = 0; ks < 2; ++ks)
                    a2[mi][ks] = *reinterpret_cast<const int4v*>(aN + (size_t)(4 + mi) * 16 * KDIM + ks * 64);
        }
        FENCE;
    }

    // ---- epilogue: C/D col = lane&15, row = 4*(lane>>4) + reg; dequant ----
    const int orow0 = bm * 256 + wr * 128 + fg * 4;
    const int ocol0 = bn * 256 + wc * 64 + fr;
#pragma unroll
    for (int mi = 0; mi < 8; ++mi)
#pragma unroll
        for (int r = 0; r < 4; ++r) {
            const int row = orow0 + mi * 16 + r;
            const float s = Sc[row];
            float* op = O + (size_t)row * NDIM + ocol0;
#pragma unroll
            for (int ni = 0; ni < 4; ++ni)
                op[ni * 16] = s * (float)acc[mi][ni][r];
        }
}

// ---------------- fallback: round-1 fused bf16 kernel ----------------
__global__ __launch_bounds__(256, 2) void binlin_fused(
        const float* __restrict__ X, const float* __restrict__ W,
        float* __restrict__ O) {
    const int tid = threadIdx.x;
    const int lane = tid & 63;
    const int wave = tid >> 6;
    const int wr = wave >> 1, wc = wave & 1;
    const int NWG = (MDIM / 128) * (NDIM / 128);
    int id = blockIdx.x;
    int swz = (id & 7) * (NWG >> 3) + (id >> 3);
    const int bm = swz >> 4, bn = swz & 15;

    __shared__ __align__(16) unsigned short As[128][40];
    __shared__ __align__(16) unsigned short Bs[128][40];

    const int rA = tid >> 3, kA = (tid & 7) * 4;
    const float* aPtr = X + (size_t)(bm * 128 + rA) * KDIM + kA;
    const int nB = (tid & 31) * 4, kB = (tid >> 5) * 4;
    const float* bPtr = W + (size_t)kB * NDIM + (size_t)bn * 128 + nB;

    float4v aReg[4], bReg[4];
#pragma unroll
    for (int p = 0; p < 4; ++p)
        aReg[p] = *reinterpret_cast<const float4v*>(aPtr + (size_t)(32 * p) * KDIM);
#pragma unroll
    for (int dk = 0; dk < 4; ++dk)
        bReg[dk] = *reinterpret_cast<const float4v*>(bPtr + (size_t)dk * NDIM);

    f32x4 acc[4][4];
#pragma unroll
    for (int i = 0; i < 4; ++i)
#pragma unroll
        for (int j = 0; j < 4; ++j) {
            acc[i][j][0] = 0.f; acc[i][j][1] = 0.f; acc[i][j][2] = 0.f; acc[i][j][3] = 0.f;
        }

    const int r16 = lane & 15, g8 = (lane >> 4) * 8;
    for (int kt = 0; kt < KDIM; kt += 32) {
#pragma unroll
        for (int p = 0; p < 4; ++p) {
            ushort4v v;
            v[0] = f2bf(aReg[p][0]); v[1] = f2bf(aReg[p][1]);
            v[2] = f2bf(aReg[p][2]); v[3] = f2bf(aReg[p][3]);
            *reinterpret_cast<ushort4v*>(&As[rA + 32 * p][kA]) = v;
        }
        unsigned short bb[4][4];
#pragma unroll
        for (int dk = 0; dk < 4; ++dk)
#pragma unroll
            for (int dn = 0; dn < 4; ++dn)
                bb[dn][dk] = (bReg[dk][dn] > 0.0f) ? (unsigned short)0x3F80u
                                                   : (unsigned short)0u;
#pragma unroll
        for (int dn = 0; dn < 4; ++dn) {
            ushort4v v;
            v[0] = bb[dn][0]; v[1] = bb[dn][1]; v[2] = bb[dn][2]; v[3] = bb[dn][3];
            *reinterpret_cast<ushort4v*>(&Bs[nB + dn][kB]) = v;
        }
        __syncthreads();
        if (kt + 32 < KDIM) {
#pragma unroll
            for (int p = 0; p < 4; ++p)
                aReg[p] = *reinterpret_cast<const float4v*>(
                    aPtr + (size_t)(32 * p) * KDIM + (kt + 32));
#pragma unroll
            for (int dk = 0; dk < 4; ++dk)
                bReg[dk] = *reinterpret_cast<const float4v*>(
                    bPtr + (size_t)(kt + 32 + dk) * NDIM);
        }
        short8 af[4], bfv[4];
#pragma unroll
        for (int mi = 0; mi < 4; ++mi)
            af[mi] = *reinterpret_cast<const short8*>(&As[wr * 64 + mi * 16 + r16][g8]);
#pragma unroll
        for (int ni = 0; ni < 4; ++ni)
            bfv[ni] = *reinterpret_cast<const short8*>(&Bs[wc * 64 + ni * 16 + r16][g8]);
#pragma unroll
        for (int mi = 0; mi < 4; ++mi)
#pragma unroll
            for (int ni = 0; ni < 4; ++ni)
                acc[mi][ni] = __builtin_amdgcn_mfma_f32_16x16x32_bf16(
                    af[mi], bfv[ni], acc[mi][ni], 0, 0, 0);
        __syncthreads();
    }

    const int orow0 = bm * 128 + wr * 64 + (lane >> 4) * 4;
    const int ocol0 = bn * 128 + wc * 64 + r16;
#pragma unroll
    for (int mi = 0; mi < 4; ++mi)
#pragma unroll
        for (int ni = 0; ni < 4; ++ni)
#pragma unroll
            for (int r = 0; r < 4; ++r)
                O[(size_t)(orow0 + mi * 16 + r) * NDIM + ocol0 + ni * 16] =
                    acc[mi][ni][r];
}

extern "C" void kernel_launch(void* const* d_in, const int* in_sizes, int n_in,
                              void* d_out, int out_size, void* d_ws, size_t ws_size,
                              hipStream_t stream) {
    const float* X = (const float*)d_in[0];
    const float* W = (const float*)d_in[1];
    float* O = (float*)d_out;
    (void)in_sizes; (void)n_in; (void)out_size;

    const size_t xq_bytes = (size_t)MDIM * KDIM;          // 16 MB
    const size_t wt_bytes = (size_t)NDIM * KDIM;          // 4 MB
    const size_t sc_bytes = (size_t)MDIM * sizeof(float); // 32 KB
    const size_t need = xq_bytes + wt_bytes + sc_bytes;

    if (ws_size >= need) {
        signed char* Xq = (signed char*)d_ws;
        signed char* Wt = Xq + xq_bytes;
        float* Sc = (float*)(Wt + wt_bytes);
        prep<<<dim3(MDIM + (KDIM / 64) * (NDIM / 64)), dim3(256), 0, stream>>>(X, W, Xq, Wt, Sc);
        gemm_tex<<<dim3((MDIM / 256) * (NDIM / 256)), dim3(512), 0, stream>>>(Xq, Wt, Sc, O);
    } else {
        binlin_fused<<<dim3((MDIM / 128) * (NDIM / 128)), dim3(256), 0, stream>>>(X, W, O);
    }
}

// Round 11
// 72.647 us; speedup vs baseline: 1.5461x; 1.5461x over previous
//
#include <hip/hip_runtime.h>

// BinaryLinear int8 path (round 11):
//   prep   : fused {X f32 -> i8 per-row quant + Sc} and {W -> {0,1} i8, NxK}
//   gemm_pv: 256x256 tile, 8 waves, BK=64, wave-PRIVATE LDS (12 KB/wave,
//            96 KB total) -> ZERO barriers in the K-loop. Each wave stages
//            its own A/B slice (gload_lds, linear, no swizzle needed at
//            64-B rows) and syncs only via its own vmcnt/lgkmcnt. Waves
//            de-phase freely => LDS port and MFMA pipe overlap (m114), and
//            epilogue writes spread out. mfma_i32_16x16x64_i8, f32 dequant.
// Fallback: round-1 fused bf16 kernel if ws too small.

#define MDIM 8192
#define NDIM 2048
#define KDIM 2048
#define NT   (KDIM / 64)          // 32 K-tiles of 64 i8

typedef __attribute__((ext_vector_type(8))) short short8;
typedef __attribute__((ext_vector_type(4))) float float4v;
typedef __attribute__((ext_vector_type(4))) float f32x4;
typedef __attribute__((ext_vector_type(4))) int int4v;
typedef __attribute__((ext_vector_type(4))) unsigned short ushort4v;
typedef __attribute__((ext_vector_type(8))) unsigned short ushort8v;

__device__ __forceinline__ unsigned short f2bf(float f) {
    union { float f; unsigned u; } v; v.f = f;
    unsigned r = v.u + 0x7FFFu + ((v.u >> 16) & 1u);
    return (unsigned short)(r >> 16);
}

__device__ __forceinline__ void gload_lds16(void* l, const void* g) {
    __builtin_amdgcn_global_load_lds(
        (const __attribute__((address_space(1))) unsigned int*)g,
        (__attribute__((address_space(3))) unsigned int*)l,
        16, 0, 0);
}

#define FENCE asm volatile("" ::: "memory")

// ---------------- pass 1 (fused): quantize X rows + binarize/transpose W ----
__global__ __launch_bounds__(256) void prep(const float* __restrict__ X,
                                            const float* __restrict__ W,
                                            signed char* __restrict__ Xq,
                                            signed char* __restrict__ Wt,
                                            float* __restrict__ Sc) {
    __shared__ __align__(16) signed char T[64][80];
    __shared__ float wm[4];
    const int t = threadIdx.x;
    const int bid = blockIdx.x;

    if (bid < MDIM) {
        const int row = bid;
        const float* xr = X + (size_t)row * KDIM + t * 8;
        float4v a = *reinterpret_cast<const float4v*>(xr);
        float4v b = *reinterpret_cast<const float4v*>(xr + 4);
        float m = fabsf(a[0]);
        m = fmaxf(m, fabsf(a[1])); m = fmaxf(m, fabsf(a[2])); m = fmaxf(m, fabsf(a[3]));
        m = fmaxf(m, fabsf(b[0])); m = fmaxf(m, fabsf(b[1]));
        m = fmaxf(m, fabsf(b[2])); m = fmaxf(m, fabsf(b[3]));
#pragma unroll
        for (int off = 32; off; off >>= 1)
            m = fmaxf(m, __shfl_xor(m, off));
        if ((t & 63) == 0) wm[t >> 6] = m;
        __syncthreads();
        const float s = fmaxf(fmaxf(wm[0], wm[1]), fmaxf(wm[2], wm[3]));
        const float inv = (s > 0.f) ? 127.0f / s : 0.f;

        int q[8];
        q[0] = __float2int_rn(a[0] * inv); q[1] = __float2int_rn(a[1] * inv);
        q[2] = __float2int_rn(a[2] * inv); q[3] = __float2int_rn(a[3] * inv);
        q[4] = __float2int_rn(b[0] * inv); q[5] = __float2int_rn(b[1] * inv);
        q[6] = __float2int_rn(b[2] * inv); q[7] = __float2int_rn(b[3] * inv);
        unsigned lo = (q[0] & 255) | ((q[1] & 255) << 8) | ((q[2] & 255) << 16) | ((unsigned)(q[3] & 255) << 24);
        unsigned hi = (q[4] & 255) | ((q[5] & 255) << 8) | ((q[6] & 255) << 16) | ((unsigned)(q[7] & 255) << 24);
        unsigned* dst = (unsigned*)(Xq + (size_t)row * KDIM + t * 8);
        dst[0] = lo; dst[1] = hi;
        if (t == 0) Sc[row] = s * (1.0f / 127.0f);
    } else {
        const int wb = bid - MDIM;
        const int k0 = (wb >> 5) * 64;
        const int n0 = (wb & 31) * 64;
        const int kr = t >> 4;
        const int nc = (t & 15) * 4;
#pragma unroll
        for (int rr = 0; rr < 4; ++rr) {
            int k = k0 + rr * 16 + kr;
            float4v w4 = *reinterpret_cast<const float4v*>(W + (size_t)k * NDIM + n0 + nc);
#pragma unroll
            for (int c = 0; c < 4; ++c)
                T[nc + c][rr * 16 + kr] = (w4[c] > 0.0f) ? (signed char)1 : (signed char)0;
        }
        __syncthreads();
        const int row = t >> 2, ch = t & 3;
        int4v v = *reinterpret_cast<const int4v*>(&T[row][ch * 16]);
        *reinterpret_cast<int4v*>(Wt + (size_t)(n0 + row) * KDIM + k0 + ch * 16) = v;
    }
}

// ---------------- pass 2: 256x256 i8 GEMM, wave-private LDS, no barriers ----
// Wave w (wr=w>>2, wc=w&3) owns LDS [w*12288, +12288): A 128 rows x 64 B at
// +0, B 64 rows x 64 B at +8192. Rows are 64 B -> frag-read bank pattern is
// uniform without swizzle, and gload_lds dest/source are both linear.
// Stage (per tile): A 8 instrs (16 rows each: lane -> row i*16+(l>>2),
// slot l&3), B 4 instrs. Frag read: lane (fr=l&15, fg=l>>4) reads 16 B at
// row mi*16+fr, slot fg. Per tile: vmcnt(0) own loads; 12 ds_read_b128;
// lgkmcnt(0); stage t+1; 32 MFMA. No __syncthreads anywhere.
__global__ __launch_bounds__(512, 1) void gemm_pv(const signed char* __restrict__ A,
                                                  const signed char* __restrict__ Bt,
                                                  const float* __restrict__ Sc,
                                                  float* __restrict__ O) {
    extern __shared__ char lds[];
    const int tid  = threadIdx.x;
    const int lane = tid & 63;
    const int w    = tid >> 6;       // 0..7
    const int wr   = w >> 2;         // 0..1
    const int wc   = w & 3;          // 0..3

    int id  = blockIdx.x;            // 256 blocks, %8==0 -> bijective
    int swz = (id & 7) * 32 + (id >> 3);
    const int bm = swz >> 3;         // 0..31
    const int bn = swz & 7;          // 0..7

    char* base = lds + w * 12288;    // private region

    // staging source: lane l -> row (l>>2), byte slot (l&3)*16
    const int lr = lane >> 2, lc = (lane & 3) * 16;
    const char* aS = (const char*)A + (size_t)(bm * 256 + wr * 128 + lr) * KDIM + lc;
    const char* bS = (const char*)Bt + (size_t)(bn * 256 + wc * 64 + lr) * KDIM + lc;

    // fragment read constants
    const int fr = lane & 15, fg = lane >> 4;
    const int fOff = fr * 64 + fg * 16;   // + mi*1024 within region

    int4v acc[8][4];
#pragma unroll
    for (int i = 0; i < 8; ++i)
#pragma unroll
        for (int j = 0; j < 4; ++j) {
            acc[i][j][0] = 0; acc[i][j][1] = 0; acc[i][j][2] = 0; acc[i][j][3] = 0;
        }

    // prologue: stage tile 0
#pragma unroll
    for (int i = 0; i < 8; ++i)
        gload_lds16(base + i * 1024, aS + (size_t)i * 16 * KDIM);
#pragma unroll
    for (int j = 0; j < 4; ++j)
        gload_lds16(base + 8192 + j * 1024, bS + (size_t)j * 16 * KDIM);

    for (int t = 0; t < NT; ++t) {
        const bool more = (t + 1 < NT);
        const char* aN = aS + (size_t)(t + 1) * 64;
        const char* bN = bS + (size_t)(t + 1) * 64;

        // own staged loads landed (per-wave counter; no barrier)
        asm volatile("s_waitcnt vmcnt(0)" ::: "memory");

        // ---- frag reads (12 x ds_read_b128) ----
        int4v af[8], bf[4];
#pragma unroll
        for (int mi = 0; mi < 8; ++mi)
            af[mi] = *reinterpret_cast<const int4v*>(base + mi * 1024 + fOff);
#pragma unroll
        for (int ni = 0; ni < 4; ++ni)
            bf[ni] = *reinterpret_cast<const int4v*>(base + 8192 + ni * 1024 + fOff);

        // all reads complete -> LDS region free for overwrite
        asm volatile("s_waitcnt lgkmcnt(0)" ::: "memory");
        __builtin_amdgcn_sched_barrier(0);

        // ---- stage tile t+1 (overlaps MFMA below) ----
        if (more) {
#pragma unroll
            for (int i = 0; i < 8; ++i)
                gload_lds16(base + i * 1024, aN + (size_t)i * 16 * KDIM);
#pragma unroll
            for (int j = 0; j < 4; ++j)
                gload_lds16(base + 8192 + j * 1024, bN + (size_t)j * 16 * KDIM);
        }

        // ---- 32 MFMA ----
        __builtin_amdgcn_s_setprio(1);
#pragma unroll
        for (int mi = 0; mi < 8; ++mi)
#pragma unroll
            for (int ni = 0; ni < 4; ++ni)
                acc[mi][ni] = __builtin_amdgcn_mfma_i32_16x16x64_i8(
                    af[mi], bf[ni], acc[mi][ni], 0, 0, 0);
        __builtin_amdgcn_s_setprio(0);
        FENCE;
    }

    // ---- epilogue: C/D col = lane&15, row = 4*(lane>>4) + reg; dequant ----
    const int orow0 = bm * 256 + wr * 128 + fg * 4;
    const int ocol0 = bn * 256 + wc * 64 + fr;
#pragma unroll
    for (int mi = 0; mi < 8; ++mi)
#pragma unroll
        for (int r = 0; r < 4; ++r) {
            const int row = orow0 + mi * 16 + r;
            const float s = Sc[row];
            float* op = O + (size_t)row * NDIM + ocol0;
#pragma unroll
            for (int ni = 0; ni < 4; ++ni)
                op[ni * 16] = s * (float)acc[mi][ni][r];
        }
}

// ---------------- fallback: round-1 fused bf16 kernel ----------------
__global__ __launch_bounds__(256, 2) void binlin_fused(
        const float* __restrict__ X, const float* __restrict__ W,
        float* __restrict__ O) {
    const int tid = threadIdx.x;
    const int lane = tid & 63;
    const int wave = tid >> 6;
    const int wr = wave >> 1, wc = wave & 1;
    const int NWG = (MDIM / 128) * (NDIM / 128);
    int id = blockIdx.x;
    int swz = (id & 7) * (NWG >> 3) + (id >> 3);
    const int bm = swz >> 4, bn = swz & 15;

    __shared__ __align__(16) unsigned short As[128][40];
    __shared__ __align__(16) unsigned short Bs[128][40];

    const int rA = tid >> 3, kA = (tid & 7) * 4;
    const float* aPtr = X + (size_t)(bm * 128 + rA) * KDIM + kA;
    const int nB = (tid & 31) * 4, kB = (tid >> 5) * 4;
    const float* bPtr = W + (size_t)kB * NDIM + (size_t)bn * 128 + nB;

    float4v aReg[4], bReg[4];
#pragma unroll
    for (int p = 0; p < 4; ++p)
        aReg[p] = *reinterpret_cast<const float4v*>(aPtr + (size_t)(32 * p) * KDIM);
#pragma unroll
    for (int dk = 0; dk < 4; ++dk)
        bReg[dk] = *reinterpret_cast<const float4v*>(bPtr + (size_t)dk * NDIM);

    f32x4 acc[4][4];
#pragma unroll
    for (int i = 0; i < 4; ++i)
#pragma unroll
        for (int j = 0; j < 4; ++j) {
            acc[i][j][0] = 0.f; acc[i][j][1] = 0.f; acc[i][j][2] = 0.f; acc[i][j][3] = 0.f;
        }

    const int r16 = lane & 15, g8 = (lane >> 4) * 8;
    for (int kt = 0; kt < KDIM; kt += 32) {
#pragma unroll
        for (int p = 0; p < 4; ++p) {
            ushort4v v;
            v[0] = f2bf(aReg[p][0]); v[1] = f2bf(aReg[p][1]);
            v[2] = f2bf(aReg[p][2]); v[3] = f2bf(aReg[p][3]);
            *reinterpret_cast<ushort4v*>(&As[rA + 32 * p][kA]) = v;
        }
        unsigned short bb[4][4];
#pragma unroll
        for (int dk = 0; dk < 4; ++dk)
#pragma unroll
            for (int dn = 0; dn < 4; ++dn)
                bb[dn][dk] = (bReg[dk][dn] > 0.0f) ? (unsigned short)0x3F80u
                                                   : (unsigned short)0u;
#pragma unroll
        for (int dn = 0; dn < 4; ++dn) {
            ushort4v v;
            v[0] = bb[dn][0]; v[1] = bb[dn][1]; v[2] = bb[dn][2]; v[3] = bb[dn][3];
            *reinterpret_cast<ushort4v*>(&Bs[nB + dn][kB]) = v;
        }
        __syncthreads();
        if (kt + 32 < KDIM) {
#pragma unroll
            for (int p = 0; p < 4; ++p)
                aReg[p] = *reinterpret_cast<const float4v*>(
                    aPtr + (size_t)(32 * p) * KDIM + (kt + 32));
#pragma unroll
            for (int dk = 0; dk < 4; ++dk)
                bReg[dk] = *reinterpret_cast<const float4v*>(
                    bPtr + (size_t)(kt + 32 + dk) * NDIM);
        }
        short8 af[4], bfv[4];
#pragma unroll
        for (int mi = 0; mi < 4; ++mi)
            af[mi] = *reinterpret_cast<const short8*>(&As[wr * 64 + mi * 16 + r16][g8]);
#pragma unroll
        for (int ni = 0; ni < 4; ++ni)
            bfv[ni] = *reinterpret_cast<const short8*>(&Bs[wc * 64 + ni * 16 + r16][g8]);
#pragma unroll
        for (int mi = 0; mi < 4; ++mi)
#pragma unroll
            for (int ni = 0; ni < 4; ++ni)
                acc[mi][ni] = __builtin_amdgcn_mfma_f32_16x16x32_bf16(
                    af[mi], bfv[ni], acc[mi][ni], 0, 0, 0);
        __syncthreads();
    }

    const int orow0 = bm * 128 + wr * 64 + (lane >> 4) * 4;
    const int ocol0 = bn * 128 + wc * 64 + r16;
#pragma unroll
    for (int mi = 0; mi < 4; ++mi)
#pragma unroll
        for (int ni = 0; ni < 4; ++ni)
#pragma unroll
            for (int r = 0; r < 4; ++r)
                O[(size_t)(orow0 + mi * 16 + r) * NDIM + ocol0 + ni * 16] =
                    acc[mi][ni][r];
}

extern "C" void kernel_launch(void* const* d_in, const int* in_sizes, int n_in,
                              void* d_out, int out_size, void* d_ws, size_t ws_size,
                              hipStream_t stream) {
    const float* X = (const float*)d_in[0];
    const float* W = (const float*)d_in[1];
    float* O = (float*)d_out;
    (void)in_sizes; (void)n_in; (void)out_size;

    const size_t xq_bytes = (size_t)MDIM * KDIM;          // 16 MB
    const size_t wt_bytes = (size_t)NDIM * KDIM;          // 4 MB
    const size_t sc_bytes = (size_t)MDIM * sizeof(float); // 32 KB
    const size_t need = xq_bytes + wt_bytes + sc_bytes;

    if (ws_size >= need) {
        signed char* Xq = (signed char*)d_ws;
        signed char* Wt = Xq + xq_bytes;
        float* Sc = (float*)(Wt + wt_bytes);
        hipFuncSetAttribute((const void*)gemm_pv,
                            hipFuncAttributeMaxDynamicSharedMemorySize, 98304);
        prep<<<dim3(MDIM + (KDIM / 64) * (NDIM / 64)), dim3(256), 0, stream>>>(X, W, Xq, Wt, Sc);
        gemm_pv<<<dim3((MDIM / 256) * (NDIM / 256)), dim3(512), 98304, stream>>>(Xq, Wt, Sc, O);
    } else {
        binlin_fused<<<dim3((MDIM / 128) * (NDIM / 128)), dim3(256), 0, stream>>>(X, W, O);
    }
}

// Round 12
// 60.935 us; speedup vs baseline: 1.8432x; 1.1922x over previous
//
#include <hip/hip_runtime.h>

// BinaryLinear int8 path (round 12):
//   prep   : fused {X f32 -> i8 per-row quant + Sc} and {W -> {0,1} i8, NxK}
//   gemm_dp: 256x128 tile, 4 waves (wave tile 128x64 = r8's proven geometry),
//            BK=64, dbuf 48KB LDS -> 2 INDEPENDENT blocks per CU. Each SIMD
//            hosts waves of different blocks (independent barriers) so one
//            block's LDS phase overlaps the other's MFMA phase; epilogue
//            bursts stagger. 64-B-row swizzle: slot' = fg ^ ((fr>>1)&3)
//            (8 bank-groups, 2-way = free), source pre-swizzled, dest linear.
//            mfma_i32_16x16x64_i8, f32 dequant epilogue.
// Fallback: round-1 fused bf16 kernel if ws too small.

#define MDIM 8192
#define NDIM 2048
#define KDIM 2048
#define NT   (KDIM / 64)          // 32 K-steps of 64 i8

typedef __attribute__((ext_vector_type(8))) short short8;
typedef __attribute__((ext_vector_type(4))) float float4v;
typedef __attribute__((ext_vector_type(4))) float f32x4;
typedef __attribute__((ext_vector_type(4))) int int4v;
typedef __attribute__((ext_vector_type(4))) unsigned short ushort4v;
typedef __attribute__((ext_vector_type(8))) unsigned short ushort8v;

__device__ __forceinline__ unsigned short f2bf(float f) {
    union { float f; unsigned u; } v; v.f = f;
    unsigned r = v.u + 0x7FFFu + ((v.u >> 16) & 1u);
    return (unsigned short)(r >> 16);
}

__device__ __forceinline__ void gload_lds16(void* l, const void* g) {
    __builtin_amdgcn_global_load_lds(
        (const __attribute__((address_space(1))) unsigned int*)g,
        (__attribute__((address_space(3))) unsigned int*)l,
        16, 0, 0);
}

#define FENCE asm volatile("" ::: "memory")
#define BAR do { FENCE; __builtin_amdgcn_s_barrier(); FENCE; } while (0)

// ---------------- pass 1 (fused): quantize X rows + binarize/transpose W ----
__global__ __launch_bounds__(256) void prep(const float* __restrict__ X,
                                            const float* __restrict__ W,
                                            signed char* __restrict__ Xq,
                                            signed char* __restrict__ Wt,
                                            float* __restrict__ Sc) {
    __shared__ __align__(16) signed char T[64][80];
    __shared__ float wm[4];
    const int t = threadIdx.x;
    const int bid = blockIdx.x;

    if (bid < MDIM) {
        const int row = bid;
        const float* xr = X + (size_t)row * KDIM + t * 8;
        float4v a = *reinterpret_cast<const float4v*>(xr);
        float4v b = *reinterpret_cast<const float4v*>(xr + 4);
        float m = fabsf(a[0]);
        m = fmaxf(m, fabsf(a[1])); m = fmaxf(m, fabsf(a[2])); m = fmaxf(m, fabsf(a[3]));
        m = fmaxf(m, fabsf(b[0])); m = fmaxf(m, fabsf(b[1]));
        m = fmaxf(m, fabsf(b[2])); m = fmaxf(m, fabsf(b[3]));
#pragma unroll
        for (int off = 32; off; off >>= 1)
            m = fmaxf(m, __shfl_xor(m, off));
        if ((t & 63) == 0) wm[t >> 6] = m;
        __syncthreads();
        const float s = fmaxf(fmaxf(wm[0], wm[1]), fmaxf(wm[2], wm[3]));
        const float inv = (s > 0.f) ? 127.0f / s : 0.f;

        int q[8];
        q[0] = __float2int_rn(a[0] * inv); q[1] = __float2int_rn(a[1] * inv);
        q[2] = __float2int_rn(a[2] * inv); q[3] = __float2int_rn(a[3] * inv);
        q[4] = __float2int_rn(b[0] * inv); q[5] = __float2int_rn(b[1] * inv);
        q[6] = __float2int_rn(b[2] * inv); q[7] = __float2int_rn(b[3] * inv);
        unsigned lo = (q[0] & 255) | ((q[1] & 255) << 8) | ((q[2] & 255) << 16) | ((unsigned)(q[3] & 255) << 24);
        unsigned hi = (q[4] & 255) | ((q[5] & 255) << 8) | ((q[6] & 255) << 16) | ((unsigned)(q[7] & 255) << 24);
        unsigned* dst = (unsigned*)(Xq + (size_t)row * KDIM + t * 8);
        dst[0] = lo; dst[1] = hi;
        if (t == 0) Sc[row] = s * (1.0f / 127.0f);
    } else {
        const int wb = bid - MDIM;
        const int k0 = (wb >> 5) * 64;
        const int n0 = (wb & 31) * 64;
        const int kr = t >> 4;
        const int nc = (t & 15) * 4;
#pragma unroll
        for (int rr = 0; rr < 4; ++rr) {
            int k = k0 + rr * 16 + kr;
            float4v w4 = *reinterpret_cast<const float4v*>(W + (size_t)k * NDIM + n0 + nc);
#pragma unroll
            for (int c = 0; c < 4; ++c)
                T[nc + c][rr * 16 + kr] = (w4[c] > 0.0f) ? (signed char)1 : (signed char)0;
        }
        __syncthreads();
        const int row = t >> 2, ch = t & 3;
        int4v v = *reinterpret_cast<const int4v*>(&T[row][ch * 16]);
        *reinterpret_cast<int4v*>(Wt + (size_t)(n0 + row) * KDIM + k0 + ch * 16) = v;
    }
}

// ---------------- pass 2: 256x128 i8 GEMM, 2 de-phased blocks/CU ----------------
// LDS per buffer (24 KB): A [256 rows][64 B] at +0, B [128 rows][64 B] at
// +16384; dbuf stride 24576 (total 48 KB). Row r, 16-B slot p holds global
// k-octet p ^ ((r&15)>>1 & 3) (via pre-swizzled global source; dest linear).
// 4 waves (2x2): wave tile 128x64 = 8mi x 4ni 16x16x64 frags, 1 ks/step.
// Per step: vmcnt(0) own stages; BAR; stage 6 (A4+B2) into nxt; 12 ds_read
// from cur; 32 MFMA (setprio).
__global__ __launch_bounds__(256, 2) void gemm_dp(const signed char* __restrict__ A,
                                                  const signed char* __restrict__ Bt,
                                                  const float* __restrict__ Sc,
                                                  float* __restrict__ O) {
    extern __shared__ char lds[];
    const int tid  = threadIdx.x;
    const int lane = tid & 63;
    const int w    = tid >> 6;       // 0..3
    const int wr   = w >> 1;         // 0..1
    const int wc   = w & 1;          // 0..1

    int id  = blockIdx.x;            // 512 blocks, %8==0 -> bijective
    int swz = (id & 7) * 64 + (id >> 3);
    const int bm = swz >> 4;         // 0..31
    const int bn = swz & 15;         // 0..15

    // staging source: lane l -> row (l>>2), pre-swizzled col ((l&3)^((l>>3)&3))
    const int lr = lane >> 2;
    const int swzcol = ((lane & 3) ^ ((lane >> 3) & 3)) << 4;
    const char* aS = (const char*)A + (size_t)(bm * 256 + w * 64 + lr) * KDIM + swzcol;
    const char* bS = (const char*)Bt + (size_t)(bn * 128 + w * 32 + lr) * KDIM + swzcol;

    // fragment read constants: fr = row%16, fg = k-octet; slot' = fg^((fr>>1)&3)
    const int fr = lane & 15, fg = lane >> 4;
    const int swz16 = (fg ^ ((fr >> 1) & 3)) << 4;
    const int aRd = wr * 8192 + fr * 64 + swz16;          // + buf + mi*1024
    const int bRd = 16384 + wc * 4096 + fr * 64 + swz16;  // + buf + ni*1024

    int4v acc[8][4];
#pragma unroll
    for (int i = 0; i < 8; ++i)
#pragma unroll
        for (int j = 0; j < 4; ++j) {
            acc[i][j][0] = 0; acc[i][j][1] = 0; acc[i][j][2] = 0; acc[i][j][3] = 0;
        }

    // prologue: stage step 0 into buf 0
#pragma unroll
    for (int i = 0; i < 4; ++i)
        gload_lds16(lds + w * 4096 + i * 1024, aS + (size_t)i * 16 * KDIM);
#pragma unroll
    for (int j = 0; j < 2; ++j)
        gload_lds16(lds + 16384 + w * 2048 + j * 1024, bS + (size_t)j * 16 * KDIM);

    for (int t = 0; t < NT; ++t) {
        const int cur = (t & 1) * 24576;
        const int nxt = ((t + 1) & 1) * 24576;
        const bool more = (t + 1 < NT);
        const char* aN = aS + (size_t)(t + 1) * 64;
        const char* bN = bS + (size_t)(t + 1) * 64;

        // own staged loads for cur landed (issued one step ago)
        asm volatile("s_waitcnt vmcnt(0)" ::: "memory");
        BAR;

        // ---- stage step t+1 into nxt ----
        if (more) {
#pragma unroll
            for (int i = 0; i < 4; ++i)
                gload_lds16(lds + nxt + w * 4096 + i * 1024, aN + (size_t)i * 16 * KDIM);
#pragma unroll
            for (int j = 0; j < 2; ++j)
                gload_lds16(lds + nxt + 16384 + w * 2048 + j * 1024, bN + (size_t)j * 16 * KDIM);
        }

        // ---- frag reads (12 x ds_read_b128) ----
        int4v af[8], bf[4];
#pragma unroll
        for (int mi = 0; mi < 8; ++mi)
            af[mi] = *reinterpret_cast<const int4v*>(lds + cur + aRd + mi * 1024);
#pragma unroll
        for (int ni = 0; ni < 4; ++ni)
            bf[ni] = *reinterpret_cast<const int4v*>(lds + cur + bRd + ni * 1024);

        // ---- 32 MFMA ----
        __builtin_amdgcn_s_setprio(1);
#pragma unroll
        for (int mi = 0; mi < 8; ++mi)
#pragma unroll
            for (int ni = 0; ni < 4; ++ni)
                acc[mi][ni] = __builtin_amdgcn_mfma_i32_16x16x64_i8(
                    af[mi], bf[ni], acc[mi][ni], 0, 0, 0);
        __builtin_amdgcn_s_setprio(0);
        FENCE;
    }

    // ---- epilogue: C/D col = lane&15, row = 4*(lane>>4) + reg; dequant ----
    const int orow0 = bm * 256 + wr * 128 + fg * 4;
    const int ocol0 = bn * 128 + wc * 64 + fr;
#pragma unroll
    for (int mi = 0; mi < 8; ++mi)
#pragma unroll
        for (int r = 0; r < 4; ++r) {
            const int row = orow0 + mi * 16 + r;
            const float s = Sc[row];
            float* op = O + (size_t)row * NDIM + ocol0;
#pragma unroll
            for (int ni = 0; ni < 4; ++ni)
                op[ni * 16] = s * (float)acc[mi][ni][r];
        }
}

// ---------------- fallback: round-1 fused bf16 kernel ----------------
__global__ __launch_bounds__(256, 2) void binlin_fused(
        const float* __restrict__ X, const float* __restrict__ W,
        float* __restrict__ O) {
    const int tid = threadIdx.x;
    const int lane = tid & 63;
    const int wave = tid >> 6;
    const int wr = wave >> 1, wc = wave & 1;
    const int NWG = (MDIM / 128) * (NDIM / 128);
    int id = blockIdx.x;
    int swz = (id & 7) * (NWG >> 3) + (id >> 3);
    const int bm = swz >> 4, bn = swz & 15;

    __shared__ __align__(16) unsigned short As[128][40];
    __shared__ __align__(16) unsigned short Bs[128][40];

    const int rA = tid >> 3, kA = (tid & 7) * 4;
    const float* aPtr = X + (size_t)(bm * 128 + rA) * KDIM + kA;
    const int nB = (tid & 31) * 4, kB = (tid >> 5) * 4;
    const float* bPtr = W + (size_t)kB * NDIM + (size_t)bn * 128 + nB;

    float4v aReg[4], bReg[4];
#pragma unroll
    for (int p = 0; p < 4; ++p)
        aReg[p] = *reinterpret_cast<const float4v*>(aPtr + (size_t)(32 * p) * KDIM);
#pragma unroll
    for (int dk = 0; dk < 4; ++dk)
        bReg[dk] = *reinterpret_cast<const float4v*>(bPtr + (size_t)dk * NDIM);

    f32x4 acc[4][4];
#pragma unroll
    for (int i = 0; i < 4; ++i)
#pragma unroll
        for (int j = 0; j < 4; ++j) {
            acc[i][j][0] = 0.f; acc[i][j][1] = 0.f; acc[i][j][2] = 0.f; acc[i][j][3] = 0.f;
        }

    const int r16 = lane & 15, g8 = (lane >> 4) * 8;
    for (int kt = 0; kt < KDIM; kt += 32) {
#pragma unroll
        for (int p = 0; p < 4; ++p) {
            ushort4v v;
            v[0] = f2bf(aReg[p][0]); v[1] = f2bf(aReg[p][1]);
            v[2] = f2bf(aReg[p][2]); v[3] = f2bf(aReg[p][3]);
            *reinterpret_cast<ushort4v*>(&As[rA + 32 * p][kA]) = v;
        }
        unsigned short bb[4][4];
#pragma unroll
        for (int dk = 0; dk < 4; ++dk)
#pragma unroll
            for (int dn = 0; dn < 4; ++dn)
                bb[dn][dk] = (bReg[dk][dn] > 0.0f) ? (unsigned short)0x3F80u
                                                   : (unsigned short)0u;
#pragma unroll
        for (int dn = 0; dn < 4; ++dn) {
            ushort4v v;
            v[0] = bb[dn][0]; v[1] = bb[dn][1]; v[2] = bb[dn][2]; v[3] = bb[dn][3];
            *reinterpret_cast<ushort4v*>(&Bs[nB + dn][kB]) = v;
        }
        __syncthreads();
        if (kt + 32 < KDIM) {
#pragma unroll
            for (int p = 0; p < 4; ++p)
                aReg[p] = *reinterpret_cast<const float4v*>(
                    aPtr + (size_t)(32 * p) * KDIM + (kt + 32));
#pragma unroll
            for (int dk = 0; dk < 4; ++dk)
                bReg[dk] = *reinterpret_cast<const float4v*>(
                    bPtr + (size_t)(kt + 32 + dk) * NDIM);
        }
        short8 af[4], bfv[4];
#pragma unroll
        for (int mi = 0; mi < 4; ++mi)
            af[mi] = *reinterpret_cast<const short8*>(&As[wr * 64 + mi * 16 + r16][g8]);
#pragma unroll
        for (int ni = 0; ni < 4; ++ni)
            bfv[ni] = *reinterpret_cast<const short8*>(&Bs[wc * 64 + ni * 16 + r16][g8]);
#pragma unroll
        for (int mi = 0; mi < 4; ++mi)
#pragma unroll
            for (int ni = 0; ni < 4; ++ni)
                acc[mi][ni] = __builtin_amdgcn_mfma_f32_16x16x32_bf16(
                    af[mi], bfv[ni], acc[mi][ni], 0, 0, 0);
        __syncthreads();
    }

    const int orow0 = bm * 128 + wr * 64 + (lane >> 4) * 4;
    const int ocol0 = bn * 128 + wc * 64 + r16;
#pragma unroll
    for (int mi = 0; mi < 4; ++mi)
#pragma unroll
        for (int ni = 0; ni < 4; ++ni)
#pragma unroll
            for (int r = 0; r < 4; ++r)
                O[(size_t)(orow0 + mi * 16 + r) * NDIM + ocol0 + ni * 16] =
                    acc[mi][ni][r];
}

extern "C" void kernel_launch(void* const* d_in, const int* in_sizes, int n_in,
                              void* d_out, int out_size, void* d_ws, size_t ws_size,
                              hipStream_t stream) {
    const float* X = (const float*)d_in[0];
    const float* W = (const float*)d_in[1];
    float* O = (float*)d_out;
    (void)in_sizes; (void)n_in; (void)out_size;

    const size_t xq_bytes = (size_t)MDIM * KDIM;          // 16 MB
    const size_t wt_bytes = (size_t)NDIM * KDIM;          // 4 MB
    const size_t sc_bytes = (size_t)MDIM * sizeof(float); // 32 KB
    const size_t need = xq_bytes + wt_bytes + sc_bytes;

    if (ws_size >= need) {
        signed char* Xq = (signed char*)d_ws;
        signed char* Wt = Xq + xq_bytes;
        float* Sc = (float*)(Wt + wt_bytes);
        hipFuncSetAttribute((const void*)gemm_dp,
                            hipFuncAttributeMaxDynamicSharedMemorySize, 49152);
        prep<<<dim3(MDIM + (KDIM / 64) * (NDIM / 64)), dim3(256), 0, stream>>>(X, W, Xq, Wt, Sc);
        gemm_dp<<<dim3((MDIM / 256) * (NDIM / 128)), dim3(256), 49152, stream>>>(Xq, Wt, Sc, O);
    } else {
        binlin_fused<<<dim3((MDIM / 128) * (NDIM / 128)), dim3(256), 0, stream>>>(X, W, O);
    }
}

// Round 13
// 55.575 us; speedup vs baseline: 2.0210x; 1.0965x over previous
//
#include <hip/hip_runtime.h>

// BinaryLinear int8 path (round 13):
//   prep   : fused {X f32 -> i8 per-row quant + Sc} and {W -> {0,1} i8, NxK}
//   gemm_mb: 256x256 tile, 1024 threads = 16 waves (4x4, wave tile 64x64),
//            BK=128, dbuf 128KB LDS, r8's 1-barrier+1-vmcnt(0) loop.
//            16 waves = 4 waves/SIMD (first config to exceed 2): read-burst
//            of some waves overlaps MFMA-burst of others on the same SIMD.
//            XOR swizzle (r8-proven, 0 conflicts), mfma_i32_16x16x64_i8,
//            f32 dequant epilogue.
// Fallback: round-1 fused bf16 kernel if ws too small.

#define MDIM 8192
#define NDIM 2048
#define KDIM 2048
#define NT   (KDIM / 128)         // 16 K-tiles of 128 i8

typedef __attribute__((ext_vector_type(8))) short short8;
typedef __attribute__((ext_vector_type(4))) float float4v;
typedef __attribute__((ext_vector_type(4))) float f32x4;
typedef __attribute__((ext_vector_type(4))) int int4v;
typedef __attribute__((ext_vector_type(4))) unsigned short ushort4v;
typedef __attribute__((ext_vector_type(8))) unsigned short ushort8v;

__device__ __forceinline__ unsigned short f2bf(float f) {
    union { float f; unsigned u; } v; v.f = f;
    unsigned r = v.u + 0x7FFFu + ((v.u >> 16) & 1u);
    return (unsigned short)(r >> 16);
}

__device__ __forceinline__ void gload_lds16(void* l, const void* g) {
    __builtin_amdgcn_global_load_lds(
        (const __attribute__((address_space(1))) unsigned int*)g,
        (__attribute__((address_space(3))) unsigned int*)l,
        16, 0, 0);
}

#define FENCE asm volatile("" ::: "memory")
#define BAR do { FENCE; __builtin_amdgcn_s_barrier(); FENCE; } while (0)

// ---------------- pass 1 (fused): quantize X rows + binarize/transpose W ----
__global__ __launch_bounds__(256) void prep(const float* __restrict__ X,
                                            const float* __restrict__ W,
                                            signed char* __restrict__ Xq,
                                            signed char* __restrict__ Wt,
                                            float* __restrict__ Sc) {
    __shared__ __align__(16) signed char T[64][80];
    __shared__ float wm[4];
    const int t = threadIdx.x;
    const int bid = blockIdx.x;

    if (bid < MDIM) {
        const int row = bid;
        const float* xr = X + (size_t)row * KDIM + t * 8;
        float4v a = *reinterpret_cast<const float4v*>(xr);
        float4v b = *reinterpret_cast<const float4v*>(xr + 4);
        float m = fabsf(a[0]);
        m = fmaxf(m, fabsf(a[1])); m = fmaxf(m, fabsf(a[2])); m = fmaxf(m, fabsf(a[3]));
        m = fmaxf(m, fabsf(b[0])); m = fmaxf(m, fabsf(b[1]));
        m = fmaxf(m, fabsf(b[2])); m = fmaxf(m, fabsf(b[3]));
#pragma unroll
        for (int off = 32; off; off >>= 1)
            m = fmaxf(m, __shfl_xor(m, off));
        if ((t & 63) == 0) wm[t >> 6] = m;
        __syncthreads();
        const float s = fmaxf(fmaxf(wm[0], wm[1]), fmaxf(wm[2], wm[3]));
        const float inv = (s > 0.f) ? 127.0f / s : 0.f;

        int q[8];
        q[0] = __float2int_rn(a[0] * inv); q[1] = __float2int_rn(a[1] * inv);
        q[2] = __float2int_rn(a[2] * inv); q[3] = __float2int_rn(a[3] * inv);
        q[4] = __float2int_rn(b[0] * inv); q[5] = __float2int_rn(b[1] * inv);
        q[6] = __float2int_rn(b[2] * inv); q[7] = __float2int_rn(b[3] * inv);
        unsigned lo = (q[0] & 255) | ((q[1] & 255) << 8) | ((q[2] & 255) << 16) | ((unsigned)(q[3] & 255) << 24);
        unsigned hi = (q[4] & 255) | ((q[5] & 255) << 8) | ((q[6] & 255) << 16) | ((unsigned)(q[7] & 255) << 24);
        unsigned* dst = (unsigned*)(Xq + (size_t)row * KDIM + t * 8);
        dst[0] = lo; dst[1] = hi;
        if (t == 0) Sc[row] = s * (1.0f / 127.0f);
    } else {
        const int wb = bid - MDIM;
        const int k0 = (wb >> 5) * 64;
        const int n0 = (wb & 31) * 64;
        const int kr = t >> 4;
        const int nc = (t & 15) * 4;
#pragma unroll
        for (int rr = 0; rr < 4; ++rr) {
            int k = k0 + rr * 16 + kr;
            float4v w4 = *reinterpret_cast<const float4v*>(W + (size_t)k * NDIM + n0 + nc);
#pragma unroll
            for (int c = 0; c < 4; ++c)
                T[nc + c][rr * 16 + kr] = (w4[c] > 0.0f) ? (signed char)1 : (signed char)0;
        }
        __syncthreads();
        const int row = t >> 2, ch = t & 3;
        int4v v = *reinterpret_cast<const int4v*>(&T[row][ch * 16]);
        *reinterpret_cast<int4v*>(Wt + (size_t)(n0 + row) * KDIM + k0 + ch * 16) = v;
    }
}

// ---------------- pass 2: 256x256 i8 GEMM, 1024-thr mega-block ----------------
// LDS per buffer (64 KB): A [256 rows][128 B] at +0, B at +32768; 16B slot s
// of row r holds global k-octet s^(r&7) (via pre-swizzled source; dest
// linear). Wave w: wr=w>>2 (0..3), wc=w&3 (0..3); wave tile 64x64 =
// 4mi x 4ni 16x16x64 frags, 2 ks per 128-B tile.
// Stage per wave: 2 A instrs (rows w*16 + {0..7}/{8..15}) + 2 B instrs.
// Per tile: vmcnt(0) [loads issued one tile ago]; BAR; stage 4 into nxt;
// read ks0 (8 b128); 16 MFMA; read ks1; 16 MFMA (setprio).
__global__ __launch_bounds__(1024, 4) void gemm_mb(const signed char* __restrict__ A,
                                                   const signed char* __restrict__ Bt,
                                                   const float* __restrict__ Sc,
                                                   float* __restrict__ O) {
    extern __shared__ char lds[];
    const int tid  = threadIdx.x;
    const int lane = tid & 63;
    const int w    = tid >> 6;       // 0..15
    const int wr   = w >> 2;         // 0..3
    const int wc   = w & 3;          // 0..3

    int id  = blockIdx.x;            // 256 blocks, %8==0 -> bijective
    int swz = (id & 7) * 32 + (id >> 3);
    const int bm = swz >> 3;         // 0..31
    const int bn = swz & 7;          // 0..7

    // staging source: lane l -> row (l>>3), pre-swizzled slot ((l&7)^(l>>3 &7))
    const int l3 = lane >> 3, l7 = lane & 7;
    const int srcOff = (w * 16 + l3) * KDIM + ((l7 ^ l3) << 4);   // rows w*16 + l3 (+8 for 2nd instr)
    const char* gA = (const char*)A + (size_t)(bm * 256) * KDIM + srcOff;
    const char* gB = (const char*)Bt + (size_t)(bn * 256) * KDIM + srcOff;

    // fragment read constants: lane l -> row l&15, 16 k-bytes at slot l>>4
    const int fr = lane & 15, fg = lane >> 4;
    const int se0 = ((fg)     ^ (fr & 7)) << 4;   // ks0: slots 0-3
    const int se1 = ((4 + fg) ^ (fr & 7)) << 4;   // ks1: slots 4-7
    const int aRd = (wr * 64 + fr) * 128;         // + buf + mi*2048 + se
    const int bRd = 32768 + (wc * 64 + fr) * 128; // + buf + ni*2048 + se

    int4v acc[4][4];
#pragma unroll
    for (int i = 0; i < 4; ++i)
#pragma unroll
        for (int j = 0; j < 4; ++j) {
            acc[i][j][0] = 0; acc[i][j][1] = 0; acc[i][j][2] = 0; acc[i][j][3] = 0;
        }

    // prologue: stage tile 0 into buf 0 (wave w stages its own 16 A-rows + 16 B-rows)
    gload_lds16(lds + w * 2048,              gA);
    gload_lds16(lds + w * 2048 + 1024,       gA + (size_t)8 * KDIM);
    gload_lds16(lds + 32768 + w * 2048,      gB);
    gload_lds16(lds + 32768 + w * 2048 + 1024, gB + (size_t)8 * KDIM);

    for (int t = 0; t < NT; ++t) {
        const int cur = (t & 1) << 16;
        const int nxt = ((t + 1) & 1) << 16;
        const bool more = (t + 1 < NT);
        const char* gAs = gA + (size_t)(t + 1) * 128;
        const char* gBs = gB + (size_t)(t + 1) * 128;

        // own staged loads for buffer cur landed (issued a full tile ago)
        asm volatile("s_waitcnt vmcnt(0)" ::: "memory");
        BAR;

        // ---- stage tile t+1 into nxt ----
        if (more) {
            gload_lds16(lds + nxt + w * 2048,                gAs);
            gload_lds16(lds + nxt + w * 2048 + 1024,         gAs + (size_t)8 * KDIM);
            gload_lds16(lds + nxt + 32768 + w * 2048,        gBs);
            gload_lds16(lds + nxt + 32768 + w * 2048 + 1024, gBs + (size_t)8 * KDIM);
        }

        // ---- ks0: read 8 frags + 16 MFMA ----
        int4v af[4], bf[4];
#pragma unroll
        for (int mi = 0; mi < 4; ++mi)
            af[mi] = *reinterpret_cast<const int4v*>(lds + cur + aRd + mi * 2048 + se0);
#pragma unroll
        for (int ni = 0; ni < 4; ++ni)
            bf[ni] = *reinterpret_cast<const int4v*>(lds + cur + bRd + ni * 2048 + se0);
        __builtin_amdgcn_s_setprio(1);
#pragma unroll
        for (int mi = 0; mi < 4; ++mi)
#pragma unroll
            for (int ni = 0; ni < 4; ++ni)
                acc[mi][ni] = __builtin_amdgcn_mfma_i32_16x16x64_i8(
                    af[mi], bf[ni], acc[mi][ni], 0, 0, 0);
        __builtin_amdgcn_s_setprio(0);

        // ---- ks1: read 8 frags + 16 MFMA ----
#pragma unroll
        for (int mi = 0; mi < 4; ++mi)
            af[mi] = *reinterpret_cast<const int4v*>(lds + cur + aRd + mi * 2048 + se1);
#pragma unroll
        for (int ni = 0; ni < 4; ++ni)
            bf[ni] = *reinterpret_cast<const int4v*>(lds + cur + bRd + ni * 2048 + se1);
        __builtin_amdgcn_s_setprio(1);
#pragma unroll
        for (int mi = 0; mi < 4; ++mi)
#pragma unroll
            for (int ni = 0; ni < 4; ++ni)
                acc[mi][ni] = __builtin_amdgcn_mfma_i32_16x16x64_i8(
                    af[mi], bf[ni], acc[mi][ni], 0, 0, 0);
        __builtin_amdgcn_s_setprio(0);
        FENCE;
    }

    // ---- epilogue: C/D col = lane&15, row = 4*(lane>>4) + reg; dequant ----
    const int orow0 = bm * 256 + wr * 64 + fg * 4;
    const int ocol0 = bn * 256 + wc * 64 + fr;
#pragma unroll
    for (int mi = 0; mi < 4; ++mi)
#pragma unroll
        for (int r = 0; r < 4; ++r) {
            const int row = orow0 + mi * 16 + r;
            const float s = Sc[row];
            float* op = O + (size_t)row * NDIM + ocol0;
#pragma unroll
            for (int ni = 0; ni < 4; ++ni)
                op[ni * 16] = s * (float)acc[mi][ni][r];
        }
}

// ---------------- fallback: round-1 fused bf16 kernel ----------------
__global__ __launch_bounds__(256, 2) void binlin_fused(
        const float* __restrict__ X, const float* __restrict__ W,
        float* __restrict__ O) {
    const int tid = threadIdx.x;
    const int lane = tid & 63;
    const int wave = tid >> 6;
    const int wr = wave >> 1, wc = wave & 1;
    const int NWG = (MDIM / 128) * (NDIM / 128);
    int id = blockIdx.x;
    int swz = (id & 7) * (NWG >> 3) + (id >> 3);
    const int bm = swz >> 4, bn = swz & 15;

    __shared__ __align__(16) unsigned short As[128][40];
    __shared__ __align__(16) unsigned short Bs[128][40];

    const int rA = tid >> 3, kA = (tid & 7) * 4;
    const float* aPtr = X + (size_t)(bm * 128 + rA) * KDIM + kA;
    const int nB = (tid & 31) * 4, kB = (tid >> 5) * 4;
    const float* bPtr = W + (size_t)kB * NDIM + (size_t)bn * 128 + nB;

    float4v aReg[4], bReg[4];
#pragma unroll
    for (int p = 0; p < 4; ++p)
        aReg[p] = *reinterpret_cast<const float4v*>(aPtr + (size_t)(32 * p) * KDIM);
#pragma unroll
    for (int dk = 0; dk < 4; ++dk)
        bReg[dk] = *reinterpret_cast<const float4v*>(bPtr + (size_t)dk * NDIM);

    f32x4 acc[4][4];
#pragma unroll
    for (int i = 0; i < 4; ++i)
#pragma unroll
        for (int j = 0; j < 4; ++j) {
            acc[i][j][0] = 0.f; acc[i][j][1] = 0.f; acc[i][j][2] = 0.f; acc[i][j][3] = 0.f;
        }

    const int r16 = lane & 15, g8 = (lane >> 4) * 8;
    for (int kt = 0; kt < KDIM; kt += 32) {
#pragma unroll
        for (int p = 0; p < 4; ++p) {
            ushort4v v;
            v[0] = f2bf(aReg[p][0]); v[1] = f2bf(aReg[p][1]);
            v[2] = f2bf(aReg[p][2]); v[3] = f2bf(aReg[p][3]);
            *reinterpret_cast<ushort4v*>(&As[rA + 32 * p][kA]) = v;
        }
        unsigned short bb[4][4];
#pragma unroll
        for (int dk = 0; dk < 4; ++dk)
#pragma unroll
            for (int dn = 0; dn < 4; ++dn)
                bb[dn][dk] = (bReg[dk][dn] > 0.0f) ? (unsigned short)0x3F80u
                                                   : (unsigned short)0u;
#pragma unroll
        for (int dn = 0; dn < 4; ++dn) {
            ushort4v v;
            v[0] = bb[dn][0]; v[1] = bb[dn][1]; v[2] = bb[dn][2]; v[3] = bb[dn][3];
            *reinterpret_cast<ushort4v*>(&Bs[nB + dn][kB]) = v;
        }
        __syncthreads();
        if (kt + 32 < KDIM) {
#pragma unroll
            for (int p = 0; p < 4; ++p)
                aReg[p] = *reinterpret_cast<const float4v*>(
                    aPtr + (size_t)(32 * p) * KDIM + (kt + 32));
#pragma unroll
            for (int dk = 0; dk < 4; ++dk)
                bReg[dk] = *reinterpret_cast<const float4v*>(
                    bPtr + (size_t)(kt + 32 + dk) * NDIM);
        }
        short8 af[4], bfv[4];
#pragma unroll
        for (int mi = 0; mi < 4; ++mi)
            af[mi] = *reinterpret_cast<const short8*>(&As[wr * 64 + mi * 16 + r16][g8]);
#pragma unroll
        for (int ni = 0; ni < 4; ++ni)
            bfv[ni] = *reinterpret_cast<const short8*>(&Bs[wc * 64 + ni * 16 + r16][g8]);
#pragma unroll
        for (int mi = 0; mi < 4; ++mi)
#pragma unroll
            for (int ni = 0; ni < 4; ++ni)
                acc[mi][ni] = __builtin_amdgcn_mfma_f32_16x16x32_bf16(
                    af[mi], bfv[ni], acc[mi][ni], 0, 0, 0);
        __syncthreads();
    }

    const int orow0 = bm * 128 + wr * 64 + (lane >> 4) * 4;
    const int ocol0 = bn * 128 + wc * 64 + r16;
#pragma unroll
    for (int mi = 0; mi < 4; ++mi)
#pragma unroll
        for (int ni = 0; ni < 4; ++ni)
#pragma unroll
            for (int r = 0; r < 4; ++r)
                O[(size_t)(orow0 + mi * 16 + r) * NDIM + ocol0 + ni * 16] =
                    acc[mi][ni][r];
}

extern "C" void kernel_launch(void* const* d_in, const int* in_sizes, int n_in,
                              void* d_out, int out_size, void* d_ws, size_t ws_size,
                              hipStream_t stream) {
    const float* X = (const float*)d_in[0];
    const float* W = (const float*)d_in[1];
    float* O = (float*)d_out;
    (void)in_sizes; (void)n_in; (void)out_size;

    const size_t xq_bytes = (size_t)MDIM * KDIM;          // 16 MB
    const size_t wt_bytes = (size_t)NDIM * KDIM;          // 4 MB
    const size_t sc_bytes = (size_t)MDIM * sizeof(float); // 32 KB
    const size_t need = xq_bytes + wt_bytes + sc_bytes;

    if (ws_size >= need) {
        signed char* Xq = (signed char*)d_ws;
        signed char* Wt = Xq + xq_bytes;
        float* Sc = (float*)(Wt + wt_bytes);
        hipFuncSetAttribute((const void*)gemm_mb,
                            hipFuncAttributeMaxDynamicSharedMemorySize, 131072);
        prep<<<dim3(MDIM + (KDIM / 64) * (NDIM / 64)), dim3(256), 0, stream>>>(X, W, Xq, Wt, Sc);
        gemm_mb<<<dim3((MDIM / 256) * (NDIM / 256)), dim3(1024), 131072, stream>>>(Xq, Wt, Sc, O);
    } else {
        binlin_fused<<<dim3((MDIM / 128) * (NDIM / 128)), dim3(256), 0, stream>>>(X, W, O);
    }
}